// Round 1
// baseline (113.243 us; speedup 1.0000x reference)
//
#include <hip/hip_runtime.h>

#define K_DIM 4096
#define N_DIM 8192

// ws float layout:
// [0,N)   : colsum0   (column sums of Hxs)      -- memset 0, atomicAdd
// [N,2N)  : prior_eps (clip(prior)+EPS)
// [2N,3N) : dope
// [3N,4N) : T  (tanh((prior_eps)*0.5)) -- valid only when Hxs == 0
// [4N,5N) : colsum_new (column sums of Hxs_new) -- memset 0, atomicAdd
// [5N]    : flag (int, nonzero => Hxs has a nonzero entry)

__device__ __forceinline__ float fast_tanh_half(float h) {
    // tanh(h/2) = 1 - 2/(e^h + 1)
    float e = __expf(h);
    float r = __builtin_amdgcn_rcpf(e + 1.0f);
    return __builtin_fmaf(-2.0f, r, 1.0f);
}

// out = clip(2*atanh(P/t), -1, 1) for t != 0, else 0.
// 2*atanh(P/t) = ln((t+P)/(t-P))
__device__ __forceinline__ float check_msg(float t, float P) {
    if (t == 0.0f) return 0.0f;
    float num = t + P;
    float den = t - P;
    float q = num * __builtin_amdgcn_rcpf(den);
    float m = 0.69314718055994531f * __log2f(q);
    return fminf(fmaxf(m, -1.0f), 1.0f);
}

// Column sums over a [K,N] f32 matrix; optional nonzero detection.
// grid = (N/1024, K/64), block = 256. Each thread: 4 consecutive cols x 64 rows.
__global__ __launch_bounds__(256) void colsum_kernel(const float* __restrict__ M,
                                                     float* __restrict__ colsum,
                                                     int* __restrict__ flag) {
    const int c0 = blockIdx.x * 1024 + threadIdx.x * 4;
    const int r0 = blockIdx.y * 64;
    const float4* p = reinterpret_cast<const float4*>(M + (size_t)r0 * N_DIM + c0);
    float sx = 0.f, sy = 0.f, sz = 0.f, sw = 0.f;
    bool nz = false;
    #pragma unroll 4
    for (int r = 0; r < 64; ++r) {
        float4 v = p[(size_t)r * (N_DIM / 4)];
        sx += v.x; sy += v.y; sz += v.z; sw += v.w;
        nz = nz || (v.x != 0.f) || (v.y != 0.f) || (v.z != 0.f) || (v.w != 0.f);
    }
    atomicAdd(&colsum[c0 + 0], sx);
    atomicAdd(&colsum[c0 + 1], sy);
    atomicAdd(&colsum[c0 + 2], sz);
    atomicAdd(&colsum[c0 + 3], sw);
    if (flag != nullptr) {
        if (__any(nz ? 1 : 0)) {
            if ((threadIdx.x & 63) == 0) atomicOr(flag, 1);
        }
    }
}

// Per-column prep: dope, prior_eps = clip(dope+phi+colsum,±100)+EPS, T = tanh(prior_eps/2)
__global__ __launch_bounds__(256) void prep_kernel(const float* __restrict__ ps,
                                                   const float* __restrict__ Min,
                                                   const float* __restrict__ colsum0,
                                                   float* __restrict__ prior_eps,
                                                   float* __restrict__ dope_out,
                                                   float* __restrict__ Tt) {
    const int n = blockIdx.x * 256 + threadIdx.x;
    if (n >= N_DIM) return;
    const float INFCAP = 100.0f;
    const float EPSV = 1e-4f;

    float p0 = ps[2 * n], p1 = ps[2 * n + 1];
    float p1n = p1 / (p0 + p1);
    float dope = logf(1.0f - p1n) - logf(p1n);

    float m0 = Min[2 * n], m1 = Min[2 * n + 1];
    float m1n = m1 / (m0 + m1);
    float phi = logf(1.0f - m1n) - logf(m1n);

    float prior = dope + phi + colsum0[n];
    prior = fminf(fmaxf(prior, -INFCAP), INFCAP);
    float pe = prior + EPSV;

    prior_eps[n] = pe;
    dope_out[n] = dope;
    Tt[n] = tanhf(pe * 0.5f);
}

// Main check-node update. grid = K blocks, 256 threads. One block per row.
__global__ __launch_bounds__(256) void row_kernel(const float* __restrict__ Hxs,
                                                  const int* __restrict__ H,
                                                  const int* __restrict__ x,
                                                  const float* __restrict__ prior_eps,
                                                  const float* __restrict__ Tt,
                                                  const int* __restrict__ flag,
                                                  float* __restrict__ out) {
    const int k = blockIdx.x;
    const int tid = threadIdx.x;
    const size_t rowoff = (size_t)k * N_DIM;
    const int4* H4 = reinterpret_cast<const int4*>(H + rowoff);
    const float4* T4 = reinterpret_cast<const float4*>(Tt);
    const float4* HX4 = reinterpret_cast<const float4*>(Hxs + rowoff);
    const float4* PE4 = reinterpret_cast<const float4*>(prior_eps);

    float t[32];
    float lp = 1.0f;

    if (*flag == 0) {
        // Fast path: Hxs is identically zero -> tanh depends only on column.
        #pragma unroll
        for (int i = 0; i < 8; ++i) {
            const int idx = i * 256 + tid;
            const int4 h = H4[idx];
            const float4 tv = T4[idx];
            float t0 = h.x ? tv.x : 0.0f;
            float t1 = h.y ? tv.y : 0.0f;
            float t2 = h.z ? tv.z : 0.0f;
            float t3 = h.w ? tv.w : 0.0f;
            t[i * 4 + 0] = t0; t[i * 4 + 1] = t1;
            t[i * 4 + 2] = t2; t[i * 4 + 3] = t3;
            lp *= (t0 == 0.0f) ? 1.0f : t0;
            lp *= (t1 == 0.0f) ? 1.0f : t1;
            lp *= (t2 == 0.0f) ? 1.0f : t2;
            lp *= (t3 == 0.0f) ? 1.0f : t3;
        }
    } else {
        // General path: Hsx = prior_eps*H - Hxs, t = tanh(Hsx/2)
        #pragma unroll
        for (int i = 0; i < 8; ++i) {
            const int idx = i * 256 + tid;
            const int4 h = H4[idx];
            const float4 hx = HX4[idx];
            const float4 pe = PE4[idx];
            float t0 = fast_tanh_half((h.x ? pe.x : 0.0f) - hx.x);
            float t1 = fast_tanh_half((h.y ? pe.y : 0.0f) - hx.y);
            float t2 = fast_tanh_half((h.z ? pe.z : 0.0f) - hx.z);
            float t3 = fast_tanh_half((h.w ? pe.w : 0.0f) - hx.w);
            t[i * 4 + 0] = t0; t[i * 4 + 1] = t1;
            t[i * 4 + 2] = t2; t[i * 4 + 3] = t3;
            lp *= (t0 == 0.0f) ? 1.0f : t0;
            lp *= (t1 == 0.0f) ? 1.0f : t1;
            lp *= (t2 == 0.0f) ? 1.0f : t2;
            lp *= (t3 == 0.0f) ? 1.0f : t3;
        }
    }

    // Block-wide product: wave butterfly then cross-wave via LDS.
    #pragma unroll
    for (int off = 1; off < 64; off <<= 1)
        lp *= __shfl_xor(lp, off);
    __shared__ float wp[4];
    if ((tid & 63) == 0) wp[tid >> 6] = lp;
    __syncthreads();
    const float prod = wp[0] * wp[1] * wp[2] * wp[3];

    const float sgn = 1.0f - 2.0f * (float)x[k];
    const float P = sgn * prod;

    float4* orow = reinterpret_cast<float4*>(out + rowoff);
    #pragma unroll
    for (int i = 0; i < 8; ++i) {
        const int idx = i * 256 + tid;
        float4 o;
        o.x = check_msg(t[i * 4 + 0], P);
        o.y = check_msg(t[i * 4 + 1], P);
        o.z = check_msg(t[i * 4 + 2], P);
        o.w = check_msg(t[i * 4 + 3], P);
        orow[idx] = o;
    }
}

// M_out from colsum(Hxs_new) + dope
__global__ __launch_bounds__(256) void final_kernel(const float* __restrict__ colsum_new,
                                                    const float* __restrict__ dope,
                                                    float* __restrict__ Mout) {
    const int n = blockIdx.x * 256 + threadIdx.x;
    if (n >= N_DIM) return;
    float z = (1.0f - tanhf((colsum_new[n] + dope[n]) * 0.5f)) * 0.5f;
    Mout[2 * n] = 1.0f - z;
    Mout[2 * n + 1] = z;
}

extern "C" void kernel_launch(void* const* d_in, const int* in_sizes, int n_in,
                              void* d_out, int out_size, void* d_ws, size_t ws_size,
                              hipStream_t stream) {
    (void)in_sizes; (void)n_in; (void)out_size; (void)ws_size;
    const float* ps  = (const float*)d_in[0];
    const float* Min = (const float*)d_in[1];
    const float* Hxs = (const float*)d_in[2];
    const int*   x   = (const int*)d_in[3];
    const int*   H   = (const int*)d_in[4];

    float* out = (float*)d_out;
    float* Mout = out;                       // N*2 floats
    float* Hxs_new = out + 2 * N_DIM;        // K*N floats

    float* ws = (float*)d_ws;
    float* colsum0    = ws;
    float* prior_eps  = ws + (size_t)N_DIM;
    float* dope       = ws + (size_t)2 * N_DIM;
    float* Tt         = ws + (size_t)3 * N_DIM;
    float* colsum_new = ws + (size_t)4 * N_DIM;
    int*   flag       = (int*)(ws + (size_t)5 * N_DIM);

    // Zero the accumulators + flag (idempotent each launch; graph-capturable)
    hipMemsetAsync(d_ws, 0, ((size_t)5 * N_DIM + 64) * sizeof(float), stream);

    dim3 csgrid(N_DIM / 1024, K_DIM / 64);
    colsum_kernel<<<csgrid, 256, 0, stream>>>(Hxs, colsum0, flag);

    prep_kernel<<<N_DIM / 256, 256, 0, stream>>>(ps, Min, colsum0, prior_eps, dope, Tt);

    row_kernel<<<K_DIM, 256, 0, stream>>>(Hxs, H, x, prior_eps, Tt, flag, Hxs_new);

    colsum_kernel<<<csgrid, 256, 0, stream>>>(Hxs_new, colsum_new, nullptr);

    final_kernel<<<N_DIM / 256, 256, 0, stream>>>(colsum_new, dope, Mout);
}